// Round 14
// baseline (584.292 us; speedup 1.0000x reference)
//
#include <hip/hip_runtime.h>
#include <cmath>

// ---------------------------------------------------------------------------
// InvariantSlotAttention forward. R14 = R13 encoder + R3-style attention grid
// (7168 blocks, one slot per block — measured 44us/launch vs 53 for fused),
// with bf16 encX, w2q folding, one-pass LN var; softmax+frames in k_softfr.
// B=16, S=7, E=HID=64, D=4096, N_ITER=3, TSOFT=0.125
// ---------------------------------------------------------------------------

#define RLOW_F 0.1f
#define RHIGH_F 0.22360679774997896f
#define W0CONST 1.00004096f      /* sum_d wts = 1 + 4096e-8 exactly */
#define SR2 704.3386243f         /* sum_d (gx^2+gy^2) */

typedef __attribute__((ext_vector_type(8))) __bf16 bf16x8;
typedef __attribute__((ext_vector_type(4))) float f32x4;

__device__ __forceinline__ float wsum64(float v){
  #pragma unroll
  for (int off = 32; off > 0; off >>= 1) v += __shfl_xor(v, off, 64);
  return v;
}
__device__ __forceinline__ float rdlane(float v, int l){
  return __int_as_float(__builtin_amdgcn_readlane(__float_as_int(v), l));
}
__device__ __forceinline__ unsigned short bf16bits(float v){
  __bf16 h = (__bf16)v;
  return *reinterpret_cast<unsigned short*>(&h);
}

// ---- phase prep core: one full wave (lanes 0..63), e = lane ---------------
__device__ __forceinline__ void pp_core(int row, int e, float qv,
    float px, float py, float sc,
    const float* __restrict__ qg_, const float* __restrict__ qb_,
    const float* __restrict__ dw, const float* __restrict__ db,
    const float* __restrict__ mlp2w, const float* __restrict__ mlp2b,
    float* __restrict__ absc, float* __restrict__ w2qc){
  float m = wsum64(qv) * (1.f/64.f);
  float d = qv - m;
  float var = wsum64(d*d) * (1.f/64.f);
  float qlnv = d * (1.0f/sqrtf(var + 1e-5f)) * qg_[e] + qb_[e];
  float A  = dw[e]      / sc;
  float Bv = dw[64 + e] / sc;
  absc[row*192 + e]       = A;
  absc[row*192 + 64 + e]  = Bv;
  absc[row*192 + 128 + e] = db[e] - px*A - py*Bv;
  float acc = 0.f;
  const float* wrow = mlp2w + e*64;
  for (int j = 0; j < 64; j++) acc = fmaf(wrow[j], rdlane(qlnv, j), acc);
  w2qc[row*68 + e] = acc;
  float c2 = wsum64(mlp2b[e] * qlnv);
  if (e == 0) w2qc[row*68 + 64] = c2;
}

// ---------------- init: queries, pos_scale, + phase-0 prep -----------------
__global__ void k_prep(const float* __restrict__ noise, const float* __restrict__ prand,
                       const float* __restrict__ mu, const float* __restrict__ logsig,
                       const float* __restrict__ qg_, const float* __restrict__ qb_,
                       const float* __restrict__ dw, const float* __restrict__ db,
                       const float* __restrict__ mlp2w, const float* __restrict__ mlp2b,
                       float* __restrict__ queries, float* __restrict__ ps,
                       float* __restrict__ absc, float* __restrict__ w2qc,
                       float* __restrict__ accF, float* __restrict__ upd){
  int row = blockIdx.x;            // b*7+s, 112 blocks
  int e = threadIdx.x;             // 64
  int s = row % 7;
  float qv = mu[e] + expf(logsig[e]) * noise[row*64 + e];
  queries[row*64 + e] = qv;
  upd[row*64 + e] = 0.f;
  if (e < 4) accF[row*4 + e] = 0.f;
  float pv = 0.f;
  if (e < 3){
    float pr = prand[row*3 + e];
    // faithful: source indexes SLOT dim; selected slots transform ALL 3 comps
    if (s < 2)       pv = pr - 0.5f;
    else if (s == 6) pv = (RLOW_F - RHIGH_F)*pr + RHIGH_F;
    else             pv = pr;
    ps[row*3 + e] = pv;
  }
  float px = rdlane(pv, 0), py = rdlane(pv, 1), sc = rdlane(pv, 2);
  pp_core(row, e, qv, px, py, sc, qg_, qb_, dw, db, mlp2w, mlp2b, absc, w2qc);
}

// ---------------- conv0: 1->64 channels, 5x5 same, relu, NHWC bf16 out -----
__global__ __launch_bounds__(256) void k_conv0(const float* __restrict__ in,
                        const float* __restrict__ w, const float* __restrict__ bias,
                        unsigned short* __restrict__ out){
  int bi = blockIdx.x; int b = bi >> 6; int y = bi & 63;   // 1024 blocks
  int t = threadIdx.x; int lane = t & 63; int xg = t >> 6;
  __shared__ float s_in[5*68];
  __shared__ float s_w[64*25];
  __shared__ float s_out[64*65];
  for (int i = t; i < 1600; i += 256) s_w[i] = w[i];
  for (int i = t; i < 340; i += 256){
    int r = i / 68, cx = i % 68;
    int yy = y + r - 2, gx = cx - 2;
    float v = 0.f;
    if (yy >= 0 && yy < 64 && gx >= 0 && gx < 64) v = in[(b*64 + yy)*64 + gx];
    s_in[r*68 + cx] = v;
  }
  __syncthreads();
  int o = lane;
  float bvv = bias[o];
  float acc[16];
  #pragma unroll
  for (int k = 0; k < 16; k++) acc[k] = bvv;
  #pragma unroll
  for (int ky = 0; ky < 5; ky++){
    float rv[20];
    const float4* p = reinterpret_cast<const float4*>(&s_in[ky*68 + xg*16]);
    #pragma unroll
    for (int q = 0; q < 5; q++){ float4 f = p[q]; rv[q*4]=f.x; rv[q*4+1]=f.y; rv[q*4+2]=f.z; rv[q*4+3]=f.w; }
    #pragma unroll
    for (int kx = 0; kx < 5; kx++){
      float wv = s_w[o*25 + ky*5 + kx];
      #pragma unroll
      for (int k = 0; k < 16; k++) acc[k] = fmaf(rv[k+kx], wv, acc[k]);
    }
  }
  #pragma unroll
  for (int k = 0; k < 16; k++) s_out[o*65 + xg*16 + k] = fmaxf(acc[k], 0.f);
  __syncthreads();
  for (int i = t; i < 4096; i += 256){
    int px = i >> 6, ch = i & 63;
    out[((size_t)(b*64 + y)*64 + px)*64 + ch] = bf16bits(s_out[ch*65 + px]);
  }
}

// ---------------- pack conv weights [O][C][5][5] -> per-tap B-frag bf16 ----
__global__ void k_packconv(const float* __restrict__ w, unsigned short* __restrict__ out){
  int idx = blockIdx.x*256 + threadIdx.x;   // 102400
  if (idx >= 102400) return;
  int j = idx & 7;
  int l = (idx >> 3) & 63;
  int frag = idx >> 9;
  int nt = frag & 3;
  int ks = (frag >> 2) % 10;
  int dy = frag / 40;
  int q = l >> 4, cr = l & 15;
  int k = ks*32 + q*8 + j;
  int kx = k >> 6, ch = k & 63;
  int n = nt*16 + cr;
  out[idx] = bf16bits(w[((n*64 + ch)*5 + dy)*5 + kx]);
}

// ---------------- conv1/conv2 bf16 MFMA implicit GEMM (512 blocks) ---------
__global__ __launch_bounds__(256) void k_convm(const unsigned short* __restrict__ in_bf,
                        const unsigned short* __restrict__ wpack,
                        const float* __restrict__ bias,
                        const float* __restrict__ lng, const float* __restrict__ lnb,
                        unsigned short* __restrict__ out_bf, int mode){
  int bi = blockIdx.x;                  // 512 = 16 b * 16 yg * 2 xh
  int b = bi >> 5; int yg = (bi >> 1) & 15; int xh = bi & 1;
  int t = threadIdx.x; int wv = t >> 6; int l = t & 63;
  int q = l >> 4, cr = l & 15;
  int yr = wv >> 1, ph = wv & 1;
  int p0 = ph*16;

  __shared__ char lds[8*36*144];

  for (int ri = 0; ri < 8; ri++){
    int yy = yg*4 + ri - 2;
    bool rok = (yy >= 0 && yy < 64);
    const uint4* src = reinterpret_cast<const uint4*>(in_bf + (size_t)(b*64 + yy)*64*64);
    for (int i = t; i < 288; i += 256){
      int px = i >> 3, c8 = i & 7;
      uint4 v = {0u,0u,0u,0u};
      int gx = xh*32 + px - 2;
      if (rok && gx >= 0 && gx < 64) v = src[gx*8 + c8];
      *reinterpret_cast<uint4*>(&lds[ri*5184 + px*144 + c8*16]) = v;
    }
  }
  __syncthreads();

  f32x4 acc[2][4];
  #pragma unroll
  for (int r = 0; r < 2; r++)
    #pragma unroll
    for (int nt = 0; nt < 4; nt++) acc[r][nt] = (f32x4){0.f,0.f,0.f,0.f};

  const bf16x8* wp = reinterpret_cast<const bf16x8*>(wpack);
  for (int dy = 0; dy < 5; dy++){
    for (int ks = 0; ks < 10; ks++){
      bf16x8 Bf[4];
      int fbase = (dy*10 + ks)*4;
      #pragma unroll
      for (int nt = 0; nt < 4; nt++) Bf[nt] = wp[(fbase + nt)*64 + l];
      int aoff = (p0 + cr + (ks >> 1))*144 + (ks & 1)*64 + q*16;
      #pragma unroll
      for (int r = 0; r < 2; r++){
        int ri = yr*2 + r + dy;
        bf16x8 a = *reinterpret_cast<const bf16x8*>(&lds[ri*5184 + aoff]);
        #pragma unroll
        for (int nt = 0; nt < 4; nt++)
          acc[r][nt] = __builtin_amdgcn_mfma_f32_16x16x32_bf16(a, Bf[nt], acc[r][nt], 0, 0, 0);
      }
    }
  }

  float bvv[4];
  #pragma unroll
  for (int nt = 0; nt < 4; nt++) bvv[nt] = bias[nt*16 + cr];

  if (mode == 0){
    #pragma unroll
    for (int r = 0; r < 2; r++){
      int y = yg*4 + yr*2 + r;
      #pragma unroll
      for (int reg = 0; reg < 4; reg++){
        int p = xh*32 + p0 + q*4 + reg;
        size_t base = ((size_t)(b*64 + y)*64 + p)*64;
        #pragma unroll
        for (int nt = 0; nt < 4; nt++)
          out_bf[base + nt*16 + cr] = bf16bits(fmaxf(acc[r][nt][reg] + bvv[nt], 0.f));
      }
    }
  } else {
    float gv[4], bb[4];
    #pragma unroll
    for (int nt = 0; nt < 4; nt++){ gv[nt] = lng[nt*16 + cr]; bb[nt] = lnb[nt*16 + cr]; }
    #pragma unroll
    for (int r = 0; r < 2; r++){
      int y = yg*4 + yr*2 + r;
      #pragma unroll
      for (int reg = 0; reg < 4; reg++){
        int p = xh*32 + p0 + q*4 + reg;
        float v[4]; float s1 = 0.f, s2 = 0.f;
        #pragma unroll
        for (int nt = 0; nt < 4; nt++){
          v[nt] = fmaxf(acc[r][nt][reg] + bvv[nt], 0.f);
          s1 += v[nt]; s2 += v[nt]*v[nt];
        }
        #pragma unroll
        for (int m = 1; m < 16; m <<= 1){ s1 += __shfl_xor(s1, m, 64); s2 += __shfl_xor(s2, m, 64); }
        float mean = s1 * (1.f/64.f);
        float var  = s2 * (1.f/64.f) - mean*mean;
        float rstd = 1.0f/sqrtf(var + 1e-5f);
        size_t base = ((size_t)b*4096 + y*64 + p)*64;
        #pragma unroll
        for (int nt = 0; nt < 4; nt++)
          out_bf[base + nt*16 + cr] = bf16bits((v[nt] - mean)*rstd*gv[nt] + bb[nt]);
      }
    }
  }
}

// ---------------- pack 64x64 f32 [k][n] into B-fragment-ordered bf16 -------
__global__ void k_packw1(const float* __restrict__ w1, unsigned short* __restrict__ out){
  int idx = blockIdx.x*256 + threadIdx.x;   // 4096
  int jj = idx & 7;
  int lane = (idx >> 3) & 63;
  int frag = idx >> 9;
  int ks = frag >> 2, nt = frag & 3;
  int q = lane >> 4, cr = lane & 15;
  int k = ks*32 + q*8 + jj;
  int n = nt*16 + cr;
  out[idx] = bf16bits(w1[k*64 + n]);
}

// ---------------- K/V projection: enc(bf16) @ toK_w, toV_w -> bf16 ---------
__global__ __launch_bounds__(256) void k_projm(const unsigned short* __restrict__ enc,
                       const unsigned short* __restrict__ kpack, const float* __restrict__ bk,
                       const unsigned short* __restrict__ vpack, const float* __restrict__ bvp,
                       unsigned short* __restrict__ K, unsigned short* __restrict__ V){
  int bi = blockIdx.x; int b = bi >> 6; int tile = bi & 63;  // 1024 blocks
  int t = threadIdx.x; int wv = t >> 6; int l = t & 63;
  int q = l >> 4, cr = l & 15;
  int d0 = tile*64 + wv*16;

  const bf16x8* kp = reinterpret_cast<const bf16x8*>(kpack);
  const bf16x8* vp = reinterpret_cast<const bf16x8*>(vpack);
  bf16x8 KB[8], VB[8];
  #pragma unroll
  for (int f = 0; f < 8; f++){ KB[f] = kp[f*64 + l]; VB[f] = vp[f*64 + l]; }

  const unsigned short* er = enc + (size_t)(b*4096 + d0 + cr)*64;
  bf16x8 a0 = *reinterpret_cast<const bf16x8*>(er + q*8);
  bf16x8 a1 = *reinterpret_cast<const bf16x8*>(er + 32 + q*8);

  f32x4 zero = {0.f,0.f,0.f,0.f};
  f32x4 aK[4], aV[4];
  #pragma unroll
  for (int nt = 0; nt < 4; nt++){
    aK[nt] = __builtin_amdgcn_mfma_f32_16x16x32_bf16(a0, KB[nt],     zero,   0, 0, 0);
    aK[nt] = __builtin_amdgcn_mfma_f32_16x16x32_bf16(a1, KB[4 + nt], aK[nt], 0, 0, 0);
    aV[nt] = __builtin_amdgcn_mfma_f32_16x16x32_bf16(a0, VB[nt],     zero,   0, 0, 0);
    aV[nt] = __builtin_amdgcn_mfma_f32_16x16x32_bf16(a1, VB[4 + nt], aV[nt], 0, 0, 0);
  }
  #pragma unroll
  for (int nt = 0; nt < 4; nt++){
    float bkv = bk[nt*16 + cr], bvv = bvp[nt*16 + cr];
    #pragma unroll
    for (int reg = 0; reg < 4; reg++){
      size_t base = ((size_t)b*4096 + d0 + q*4 + reg)*64 + nt*16 + cr;
      K[base] = bf16bits(aK[nt][reg] + bkv);
      V[base] = bf16bits(aV[nt][reg] + bvv);
    }
  }
}

// ---------------- attention K-pass: 7168 blocks, one slot each -------------
// logit = (relu(LN(x)@W1+b1) . w2q + c2) * 0.125, x = encK + affine(slot)
__global__ __launch_bounds__(256) void k_attnK7(const unsigned short* __restrict__ encX,
     const unsigned short* __restrict__ w1pack, const float* __restrict__ mlp1b,
     const float* __restrict__ absc, const float* __restrict__ qg_,
     const float* __restrict__ qb_, const float* __restrict__ w2qc,
     float* __restrict__ logits){
  int bi = blockIdx.x;                 // 7168 = 112 bs * 64 tiles
  int tile = bi & 63; int bs = bi >> 6;
  int b = bs / 7;
  int t = threadIdx.x; int wv = t >> 6; int l = t & 63;
  int q = l >> 4, cr = l & 15;
  int m0 = tile*64 + wv*16;
  int drow = m0 + cr;

  const bf16x8* wp = reinterpret_cast<const bf16x8*>(w1pack);
  bf16x8 Bf[8];
  #pragma unroll
  for (int f = 0; f < 8; f++) Bf[f] = wp[f*64 + l];

  const float* Ac = absc + bs*192;
  const unsigned short* er = encX + (size_t)(b*4096 + drow)*64;
  float gx = -0.5f + (float)(drow & 63) * (1.f/63.f);
  float gy = -0.5f + (float)((drow >> 6) & 63) * (1.f/63.f);
  float x[16];
  {
    bf16x8 ea = *reinterpret_cast<const bf16x8*>(er + q*8);
    bf16x8 eb = *reinterpret_cast<const bf16x8*>(er + 32 + q*8);
    #pragma unroll
    for (int i = 0; i < 8; i++){ x[i] = (float)ea[i]; x[8+i] = (float)eb[i]; }
  }
  float gq[16], bq[16];
  #pragma unroll
  for (int h = 0; h < 2; h++){
    int fb = h ? (32 + q*8) : (q*8);
    const float4* A4 = reinterpret_cast<const float4*>(Ac + fb);
    const float4* B4 = reinterpret_cast<const float4*>(Ac + 64 + fb);
    const float4* C4 = reinterpret_cast<const float4*>(Ac + 128 + fb);
    const float4* g4 = reinterpret_cast<const float4*>(qg_ + fb);
    const float4* b4 = reinterpret_cast<const float4*>(qb_ + fb);
    #pragma unroll
    for (int p = 0; p < 2; p++){
      float4 Av = A4[p], Bv = B4[p], Cv = C4[p], gg = g4[p], bb = b4[p];
      int o = h*8 + p*4;
      x[o+0] += gx*Av.x + gy*Bv.x + Cv.x;
      x[o+1] += gx*Av.y + gy*Bv.y + Cv.y;
      x[o+2] += gx*Av.z + gy*Bv.z + Cv.z;
      x[o+3] += gx*Av.w + gy*Bv.w + Cv.w;
      gq[o+0]=gg.x; gq[o+1]=gg.y; gq[o+2]=gg.z; gq[o+3]=gg.w;
      bq[o+0]=bb.x; bq[o+1]=bb.y; bq[o+2]=bb.z; bq[o+3]=bb.w;
    }
  }
  float s1 = 0.f, s2 = 0.f;
  #pragma unroll
  for (int k = 0; k < 16; k++){ s1 += x[k]; s2 = fmaf(x[k], x[k], s2); }
  s1 += __shfl_xor(s1, 16, 64); s2 += __shfl_xor(s2, 16, 64);
  s1 += __shfl_xor(s1, 32, 64); s2 += __shfl_xor(s2, 32, 64);
  float m = s1 * (1.f/64.f);
  float rstd = 1.0f/sqrtf(s2*(1.f/64.f) - m*m + 1e-5f);

  bf16x8 a0, a1;
  #pragma unroll
  for (int k = 0; k < 8; k++){
    a0[k] = (__bf16)((x[k]   - m)*rstd*gq[k]   + bq[k]);
    a1[k] = (__bf16)((x[8+k] - m)*rstd*gq[8+k] + bq[8+k]);
  }

  f32x4 zero = {0.f, 0.f, 0.f, 0.f};
  f32x4 acc[4];
  #pragma unroll
  for (int nt = 0; nt < 4; nt++){
    acc[nt] = __builtin_amdgcn_mfma_f32_16x16x32_bf16(a0, Bf[nt],     zero,    0, 0, 0);
    acc[nt] = __builtin_amdgcn_mfma_f32_16x16x32_bf16(a1, Bf[4 + nt], acc[nt], 0, 0, 0);
  }

  const float* wq = w2qc + bs*68;
  float c2 = wq[64];
  float p[4] = {0.f, 0.f, 0.f, 0.f};
  #pragma unroll
  for (int nt = 0; nt < 4; nt++){
    float bb  = mlp1b[nt*16 + cr];
    float wqv = wq[nt*16 + cr];
    #pragma unroll
    for (int reg = 0; reg < 4; reg++){
      float y = fmaxf(acc[nt][reg] + bb, 0.f);
      p[reg] = fmaf(y, wqv, p[reg]);
    }
  }
  #pragma unroll
  for (int reg = 0; reg < 4; reg++){
    #pragma unroll
    for (int off = 1; off < 16; off <<= 1) p[reg] += __shfl_xor(p[reg], off, 64);
  }
  if (cr == 0){
    #pragma unroll
    for (int reg = 0; reg < 4; reg++)
      logits[(size_t)bs*4096 + m0 + q*4 + reg] = (p[reg] + c2) * 0.125f;
  }
}

// ---------------- softmax over slots + frames partials + att store ---------
__global__ void k_softfr(const float* __restrict__ logits, float* __restrict__ attout,
                         float* __restrict__ accF){
  int bi = blockIdx.x;                 // 256 = 16 b * 16 groups
  int b = bi >> 4;
  int t = threadIdx.x;
  int d = (bi & 15)*256 + t;
  int lane = t & 63;
  float lv[7];
  #pragma unroll
  for (int s = 0; s < 7; s++) lv[s] = logits[(size_t)(b*7+s)*4096 + d];
  float mx = lv[0];
  #pragma unroll
  for (int s = 1; s < 7; s++) mx = fmaxf(mx, lv[s]);
  float sm = 0.f;
  #pragma unroll
  for (int s = 0; s < 7; s++){ lv[s] = expf(lv[s] - mx); sm += lv[s]; }
  float inv = 1.0f / sm;
  float gx = -0.5f + (float)(d & 63) * (1.f/63.f);
  float gy = -0.5f + (float)(d >> 6) * (1.f/63.f);
  float r2 = gx*gx + gy*gy;
  #pragma unroll
  for (int s = 0; s < 7; s++){
    float a = lv[s] * inv;
    attout[(size_t)(b*7+s)*4096 + d] = a;
    float w0 = wsum64(a);
    float w1 = wsum64(a*gx);
    float w2 = wsum64(a*gy);
    float w3 = wsum64(a*r2);
    if (lane == 0){
      atomicAdd(&accF[(b*7+s)*4 + 0], w0);
      atomicAdd(&accF[(b*7+s)*4 + 1], w1);
      atomicAdd(&accF[(b*7+s)*4 + 2], w2);
      atomicAdd(&accF[(b*7+s)*4 + 3], w3);
    }
  }
}

// ---------------- attention V-pass: 7168 blocks, one slot each -------------
// upd_pre[bs][n] += sum_d wts_d * relu(LN(xV)@W1+b1)[n]
__global__ __launch_bounds__(256) void k_attnV7(const unsigned short* __restrict__ encX,
     const unsigned short* __restrict__ w1pack, const float* __restrict__ mlp1b,
     const float* __restrict__ absc, const float* __restrict__ qg_,
     const float* __restrict__ qb_, const float* __restrict__ att,
     const float* __restrict__ accF, float* __restrict__ upd){
  int bi = blockIdx.x;                 // 7168
  int tile = bi & 63; int bs = bi >> 6;
  int b = bs / 7;
  int t = threadIdx.x; int wv = t >> 6; int l = t & 63;
  int q = l >> 4, cr = l & 15;
  int m0 = tile*64 + wv*16;
  int drow = m0 + cr;

  __shared__ float red[4][64];

  const bf16x8* wp = reinterpret_cast<const bf16x8*>(w1pack);
  bf16x8 Bf[8];
  #pragma unroll
  for (int f = 0; f < 8; f++) Bf[f] = wp[f*64 + l];

  const float* Ac = absc + bs*192;
  const unsigned short* er = encX + (size_t)(b*4096 + drow)*64;
  float gx = -0.5f + (float)(drow & 63) * (1.f/63.f);
  float gy = -0.5f + (float)((drow >> 6) & 63) * (1.f/63.f);
  float x[16];
  {
    bf16x8 ea = *reinterpret_cast<const bf16x8*>(er + q*8);
    bf16x8 eb = *reinterpret_cast<const bf16x8*>(er + 32 + q*8);
    #pragma unroll
    for (int i = 0; i < 8; i++){ x[i] = (float)ea[i]; x[8+i] = (float)eb[i]; }
  }
  float gq[16], bq[16];
  #pragma unroll
  for (int h = 0; h < 2; h++){
    int fb = h ? (32 + q*8) : (q*8);
    const float4* A4 = reinterpret_cast<const float4*>(Ac + fb);
    const float4* B4 = reinterpret_cast<const float4*>(Ac + 64 + fb);
    const float4* C4 = reinterpret_cast<const float4*>(Ac + 128 + fb);
    const float4* g4 = reinterpret_cast<const float4*>(qg_ + fb);
    const float4* b4 = reinterpret_cast<const float4*>(qb_ + fb);
    #pragma unroll
    for (int p = 0; p < 2; p++){
      float4 Av = A4[p], Bv = B4[p], Cv = C4[p], gg = g4[p], bb = b4[p];
      int o = h*8 + p*4;
      x[o+0] += gx*Av.x + gy*Bv.x + Cv.x;
      x[o+1] += gx*Av.y + gy*Bv.y + Cv.y;
      x[o+2] += gx*Av.z + gy*Bv.z + Cv.z;
      x[o+3] += gx*Av.w + gy*Bv.w + Cv.w;
      gq[o+0]=gg.x; gq[o+1]=gg.y; gq[o+2]=gg.z; gq[o+3]=gg.w;
      bq[o+0]=bb.x; bq[o+1]=bb.y; bq[o+2]=bb.z; bq[o+3]=bb.w;
    }
  }
  float s1 = 0.f, s2 = 0.f;
  #pragma unroll
  for (int k = 0; k < 16; k++){ s1 += x[k]; s2 = fmaf(x[k], x[k], s2); }
  s1 += __shfl_xor(s1, 16, 64); s2 += __shfl_xor(s2, 16, 64);
  s1 += __shfl_xor(s1, 32, 64); s2 += __shfl_xor(s2, 32, 64);
  float m = s1 * (1.f/64.f);
  float rstd = 1.0f/sqrtf(s2*(1.f/64.f) - m*m + 1e-5f);

  bf16x8 a0, a1;
  #pragma unroll
  for (int k = 0; k < 8; k++){
    a0[k] = (__bf16)((x[k]   - m)*rstd*gq[k]   + bq[k]);
    a1[k] = (__bf16)((x[8+k] - m)*rstd*gq[8+k] + bq[8+k]);
  }

  f32x4 zero = {0.f, 0.f, 0.f, 0.f};
  f32x4 acc[4];
  #pragma unroll
  for (int nt = 0; nt < 4; nt++){
    acc[nt] = __builtin_amdgcn_mfma_f32_16x16x32_bf16(a0, Bf[nt],     zero,    0, 0, 0);
    acc[nt] = __builtin_amdgcn_mfma_f32_16x16x32_bf16(a1, Bf[4 + nt], acc[nt], 0, 0, 0);
  }

  float isa = 1.0f / accF[bs*4];
  float wr[4];
  #pragma unroll
  for (int reg = 0; reg < 4; reg++)
    wr[reg] = fmaf(att[(size_t)bs*4096 + m0 + q*4 + reg], isa, 1e-8f);
  float pc[4];
  #pragma unroll
  for (int nt = 0; nt < 4; nt++){
    pc[nt] = 0.f;
    float bb = mlp1b[nt*16 + cr];
    #pragma unroll
    for (int reg = 0; reg < 4; reg++)
      pc[nt] = fmaf(wr[reg], fmaxf(acc[nt][reg] + bb, 0.f), pc[nt]);
  }
  #pragma unroll
  for (int nt = 0; nt < 4; nt++){
    pc[nt] += __shfl_xor(pc[nt], 16, 64);
    pc[nt] += __shfl_xor(pc[nt], 32, 64);
  }
  if (q == 0){
    #pragma unroll
    for (int nt = 0; nt < 4; nt++) red[wv][nt*16 + cr] = pc[nt];
  }
  __syncthreads();
  if (t < 64) atomicAdd(&upd[bs*64 + t], red[0][t] + red[1][t] + red[2][t] + red[3][t]);
}

// ---------------- GRU cell + frames finalize + next-phase prep -------------
__global__ void k_gru(float* __restrict__ upd, float* __restrict__ queries,
                      const float* __restrict__ wih, const float* __restrict__ whh,
                      const float* __restrict__ bih, const float* __restrict__ bhh,
                      const float* __restrict__ mlp2w, const float* __restrict__ mlp2b,
                      float* __restrict__ accF, float* __restrict__ ps,
                      const float* __restrict__ qg_, const float* __restrict__ qb_,
                      const float* __restrict__ dw, const float* __restrict__ db,
                      float* __restrict__ absc, float* __restrict__ w2qc){
  int row = blockIdx.x; int t = threadIdx.x;   // 112 x 192
  __shared__ float us[64], hs[64], xs[64], gis[192], ghs[192];
  __shared__ float s_ps3[3];
  if (t < 64){ us[t] = upd[row*64 + t]; hs[t] = queries[row*64 + t]; }
  if (t == 64){
    float sa = accF[row*4+0];
    float ax = accF[row*4+1], ay = accF[row*4+2], ar2 = accF[row*4+3];
    float isa = 1.0f/sa;
    float Wx = ax*isa, Wy = ay*isa;
    float Wg = ar2*isa + 1e-8f*SR2;
    float s2 = Wg - (Wx*Wx + Wy*Wy)*(2.f - W0CONST);
    s_ps3[0] = Wx; s_ps3[1] = Wy; s_ps3[2] = sqrtf(fmaxf(s2, 0.f));
  }
  __syncthreads();
  if (t < 64){
    float a = W0CONST * mlp2b[t];
    for (int i = 0; i < 64; i++) a = fmaf(us[i], mlp2w[i*64 + t], a);
    xs[t] = a;
  }
  __syncthreads();
  float gi = bih[t], gh = bhh[t];
  for (int e = 0; e < 64; e++){
    gi = fmaf(wih[t*64 + e], xs[e], gi);
    gh = fmaf(whh[t*64 + e], hs[e], gh);
  }
  gis[t] = gi; ghs[t] = gh;
  __syncthreads();
  if (t < 64){
    float r = 1.0f/(1.0f + expf(-(gis[t]      + ghs[t])));
    float z = 1.0f/(1.0f + expf(-(gis[64+t]   + ghs[64+t])));
    float n = tanhf(gis[128+t] + r*ghs[128+t]);
    float newq = (1.0f - z)*n + z*hs[t];
    queries[row*64 + t] = newq;
    upd[row*64 + t] = 0.f;
    if (t < 4) accF[row*4 + t] = 0.f;
    if (t < 3) ps[row*3 + t] = s_ps3[t];
    pp_core(row, t, newq, s_ps3[0], s_ps3[1], s_ps3[2],
            qg_, qb_, dw, db, mlp2w, mlp2b, absc, w2qc);
  }
}

// ---------------- heads: alpha, slot_feat(+frames), copy queries -----------
__global__ void k_final(const float* __restrict__ queries, const float* __restrict__ accF,
                        const float* __restrict__ a1w, const float* __restrict__ a1b,
                        const float* __restrict__ a2w, const float* __restrict__ a2b,
                        const float* __restrict__ f1w, const float* __restrict__ f1b,
                        const float* __restrict__ f2w, const float* __restrict__ f2b,
                        float* __restrict__ out){
  int bs = blockIdx.x; int e = threadIdx.x;    // 112 x 64
  __shared__ float qs[64], hf[64], ha[32];
  float q = queries[bs*64 + e];
  qs[e] = q;
  out[bs*64 + e] = q;
  __syncthreads();
  float accf = f1b[e];
  for (int i = 0; i < 64; i++) accf = fmaf(qs[i], f1w[i*64 + e], accf);
  hf[e] = fmaxf(accf, 0.f);
  if (e < 32){
    float acca = a1b[e];
    for (int i = 0; i < 64; i++) acca = fmaf(qs[i], a1w[i*32 + e], acca);
    ha[e] = fmaxf(acca, 0.f);
  }
  __syncthreads();
  if (e < 3){
    float sf = f2b[e];
    for (int o = 0; o < 64; o++) sf = fmaf(hf[o], f2w[o*3 + e], sf);
    float sa = accF[bs*4+0], ax = accF[bs*4+1], ay = accF[bs*4+2], ar2 = accF[bs*4+3];
    float isa = 1.0f/sa;
    float Wx = ax*isa, Wy = ay*isa;
    float Wg = ar2*isa + 1e-8f*SR2;
    float s2 = Wg - (Wx*Wx + Wy*Wy)*(2.f - W0CONST);
    float nv = (e == 0) ? Wx : ((e == 1) ? Wy : sqrtf(fmaxf(s2, 0.f)));
    out[465920 + bs*3 + e] = sf + nv;
  }
  if (e == 32){
    float al = a2b[0];
    for (int o = 0; o < 32; o++) al = fmaf(ha[o], a2w[o], al);
    out[466256 + bs] = 1.0f/(1.0f + expf(-al));
  }
}

// ---------------------------------------------------------------------------
extern "C" void kernel_launch(void* const* d_in, const int* in_sizes, int n_in,
                              void* d_out, int out_size, void* d_ws, size_t ws_size,
                              hipStream_t stream){
  const float* data        = (const float*)d_in[0];
  const float* slot_noise  = (const float*)d_in[1];
  const float* pos_rand    = (const float*)d_in[2];
  const float* conv0_w     = (const float*)d_in[3];
  const float* conv0_b     = (const float*)d_in[4];
  const float* conv1_w     = (const float*)d_in[5];
  const float* conv1_b     = (const float*)d_in[6];
  const float* conv2_w     = (const float*)d_in[7];
  const float* conv2_b     = (const float*)d_in[8];
  const float* dataN_g     = (const float*)d_in[9];
  const float* dataN_b     = (const float*)d_in[10];
  const float* queryN_g    = (const float*)d_in[11];
  const float* queryN_b    = (const float*)d_in[12];
  const float* toK_w       = (const float*)d_in[13];
  const float* toK_b       = (const float*)d_in[14];
  const float* toV_w       = (const float*)d_in[15];
  const float* toV_b       = (const float*)d_in[16];
  const float* dense_w     = (const float*)d_in[17];
  const float* dense_b     = (const float*)d_in[18];
  const float* mlp1_w      = (const float*)d_in[19];
  const float* mlp1_b      = (const float*)d_in[20];
  const float* mlp2_w      = (const float*)d_in[21];
  const float* mlp2_b      = (const float*)d_in[22];
  const float* gru_wih     = (const float*)d_in[23];
  const float* gru_whh     = (const float*)d_in[24];
  const float* gru_bih     = (const float*)d_in[25];
  const float* gru_bhh     = (const float*)d_in[26];
  const float* alpha1_w    = (const float*)d_in[27];
  const float* alpha1_b    = (const float*)d_in[28];
  const float* alpha2_w    = (const float*)d_in[29];
  const float* alpha2_b    = (const float*)d_in[30];
  const float* final1_w    = (const float*)d_in[31];
  const float* final1_b    = (const float*)d_in[32];
  const float* final2_w    = (const float*)d_in[33];
  const float* final2_b    = (const float*)d_in[34];
  const float* slots_mu    = (const float*)d_in[35];
  const float* slots_lsig  = (const float*)d_in[36];

  float* ws   = (float*)d_ws;
  float* bufA = ws;                    // c0_bf (bf16) then encK (bf16)
  float* bufB = bufA + 4194304;        // enc bf16
  float* bufC = bufB + 4194304;        // c1_bf (bf16) then encV (bf16)
  float* attw = bufC + 4194304;        // 458,752 (logits/att, all phases)
  float* queries = attw + 458752;      // 7,168
  float* ps   = queries + 7168;        // 512 ([112][3], 336 used)
  float* absc = ps + 512;              // 21,504 (A/B/cc per (b,s))
  float* accF = absc + 21504;          // 512 ([112][4]: sa, ax, ay, ar2)
  float* upd  = accF + 512;            // 7,168
  float* w2qc = upd + 7168;            // 7,616 ([112][68])
  unsigned short* w1pack = (unsigned short*)(w2qc + 7616);   // 4096 bf16
  unsigned short* kpack  = w1pack + 4096;                    // 4096
  unsigned short* vpack  = kpack + 4096;                     // 4096
  unsigned short* wp1    = vpack + 4096;                     // 102,400
  unsigned short* wp2    = wp1 + 102400;                     // 102,400

  unsigned short* c0_bf = (unsigned short*)bufA;   // conv0 out, NHWC bf16
  unsigned short* c1_bf = (unsigned short*)bufC;   // conv1 out, NHWC bf16
  unsigned short* enc   = (unsigned short*)bufB;   // LN(conv2) bf16
  unsigned short* encK  = (unsigned short*)bufA;   // overwrites c0_bf (done)
  unsigned short* encV  = (unsigned short*)bufC;   // overwrites c1_bf (done)

  float* outq   = (float*)d_out;       // queries [7168]
  float* outatt = outq + 7168;         // att [458752]

  k_prep<<<112, 64, 0, stream>>>(slot_noise, pos_rand, slots_mu, slots_lsig,
                                 queryN_g, queryN_b, dense_w, dense_b, mlp2_w, mlp2_b,
                                 queries, ps, absc, w2qc, accF, upd);
  k_packw1<<<16, 256, 0, stream>>>(mlp1_w, w1pack);
  k_packw1<<<16, 256, 0, stream>>>(toK_w, kpack);
  k_packw1<<<16, 256, 0, stream>>>(toV_w, vpack);
  k_packconv<<<400, 256, 0, stream>>>(conv1_w, wp1);
  k_packconv<<<400, 256, 0, stream>>>(conv2_w, wp2);
  k_conv0<<<1024, 256, 0, stream>>>(data, conv0_w, conv0_b, c0_bf);
  k_convm<<<512, 256, 0, stream>>>(c0_bf, wp1, conv1_b, nullptr, nullptr, c1_bf, 0);
  k_convm<<<512, 256, 0, stream>>>(c1_bf, wp2, conv2_b, dataN_g, dataN_b, enc, 1);
  k_projm<<<1024, 256, 0, stream>>>(enc, kpack, toK_b, vpack, toV_b, encK, encV);

  for (int p = 0; p < 4; p++){
    float* attp = (p == 3) ? outatt : attw;
    k_attnK7<<<7168, 256, 0, stream>>>(encK, w1pack, mlp1_b, absc, queryN_g, queryN_b,
                                       w2qc, attw);
    k_softfr<<<256, 256, 0, stream>>>(attw, attp, accF);
    if (p < 3){
      k_attnV7<<<7168, 256, 0, stream>>>(encV, w1pack, mlp1_b, absc, queryN_g, queryN_b,
                                         attp, accF, upd);
      k_gru<<<112, 192, 0, stream>>>(upd, queries, gru_wih, gru_whh, gru_bih, gru_bhh,
                                     mlp2_w, mlp2_b, accF, ps, queryN_g, queryN_b,
                                     dense_w, dense_b, absc, w2qc);
    }
  }
  k_final<<<112, 64, 0, stream>>>(queries, accF,
                                  alpha1_w, alpha1_b, alpha2_w, alpha2_b,
                                  final1_w, final1_b, final2_w, final2_b, outq);
}

// Round 15
// 520.357 us; speedup vs baseline: 1.1229x; 1.1229x over previous
//
#include <hip/hip_runtime.h>
#include <cmath>

// ---------------------------------------------------------------------------
// InvariantSlotAttention forward. R15 = exact revert to R13 (champion, 527us):
// R11 slot-paired attention + split-x conv + bf16 enc. Six structural
// attention variants (R6,R7,R9,R12,R14) all regressed; this is the plateau
// shape. All hot kernels latency-bound (VALUBusy<25%, HBM<4%, MfmaUtil<4%).
// B=16, S=7, E=HID=64, D=4096, N_ITER=3, TSOFT=0.125
// ---------------------------------------------------------------------------

#define RLOW_F 0.1f
#define RHIGH_F 0.22360679774997896f
#define W0CONST 1.00004096f      /* sum_d wts = 1 + 4096e-8 exactly */
#define SR2 704.3386243f         /* sum_d (gx^2+gy^2) */

typedef __attribute__((ext_vector_type(8))) __bf16 bf16x8;
typedef __attribute__((ext_vector_type(4))) float f32x4;

__device__ __forceinline__ float wsum64(float v){
  #pragma unroll
  for (int off = 32; off > 0; off >>= 1) v += __shfl_xor(v, off, 64);
  return v;
}
__device__ __forceinline__ float rdlane(float v, int l){
  return __int_as_float(__builtin_amdgcn_readlane(__float_as_int(v), l));
}
__device__ __forceinline__ unsigned short bf16bits(float v){
  __bf16 h = (__bf16)v;
  return *reinterpret_cast<unsigned short*>(&h);
}

// ---- phase prep core: one full wave (lanes 0..63), e = lane ---------------
__device__ __forceinline__ void pp_core(int row, int e, float qv,
    float px, float py, float sc,
    const float* __restrict__ qg_, const float* __restrict__ qb_,
    const float* __restrict__ dw, const float* __restrict__ db,
    const float* __restrict__ mlp2w, const float* __restrict__ mlp2b,
    float* __restrict__ absc, float* __restrict__ w2qc){
  float m = wsum64(qv) * (1.f/64.f);
  float d = qv - m;
  float var = wsum64(d*d) * (1.f/64.f);
  float qlnv = d * (1.0f/sqrtf(var + 1e-5f)) * qg_[e] + qb_[e];
  float A  = dw[e]      / sc;
  float Bv = dw[64 + e] / sc;
  absc[row*192 + e]       = A;
  absc[row*192 + 64 + e]  = Bv;
  absc[row*192 + 128 + e] = db[e] - px*A - py*Bv;
  float acc = 0.f;
  const float* wrow = mlp2w + e*64;
  for (int j = 0; j < 64; j++) acc = fmaf(wrow[j], rdlane(qlnv, j), acc);
  w2qc[row*68 + e] = acc;
  float c2 = wsum64(mlp2b[e] * qlnv);
  if (e == 0) w2qc[row*68 + 64] = c2;
}

// ---------------- init: queries, pos_scale, + phase-0 prep -----------------
__global__ void k_prep(const float* __restrict__ noise, const float* __restrict__ prand,
                       const float* __restrict__ mu, const float* __restrict__ logsig,
                       const float* __restrict__ qg_, const float* __restrict__ qb_,
                       const float* __restrict__ dw, const float* __restrict__ db,
                       const float* __restrict__ mlp2w, const float* __restrict__ mlp2b,
                       float* __restrict__ queries, float* __restrict__ ps,
                       float* __restrict__ absc, float* __restrict__ w2qc,
                       float* __restrict__ accF, float* __restrict__ upd){
  int row = blockIdx.x;            // b*7+s, 112 blocks
  int e = threadIdx.x;             // 64
  int s = row % 7;
  float qv = mu[e] + expf(logsig[e]) * noise[row*64 + e];
  queries[row*64 + e] = qv;
  upd[row*64 + e] = 0.f;
  if (e < 4) accF[row*4 + e] = 0.f;
  float pv = 0.f;
  if (e < 3){
    float pr = prand[row*3 + e];
    // faithful: source indexes SLOT dim; selected slots transform ALL 3 comps
    if (s < 2)       pv = pr - 0.5f;
    else if (s == 6) pv = (RLOW_F - RHIGH_F)*pr + RHIGH_F;
    else             pv = pr;
    ps[row*3 + e] = pv;
  }
  float px = rdlane(pv, 0), py = rdlane(pv, 1), sc = rdlane(pv, 2);
  pp_core(row, e, qv, px, py, sc, qg_, qb_, dw, db, mlp2w, mlp2b, absc, w2qc);
}

// ---------------- conv0: 1->64 channels, 5x5 same, relu, NHWC bf16 out -----
__global__ __launch_bounds__(256) void k_conv0(const float* __restrict__ in,
                        const float* __restrict__ w, const float* __restrict__ bias,
                        unsigned short* __restrict__ out){
  int bi = blockIdx.x; int b = bi >> 6; int y = bi & 63;   // 1024 blocks
  int t = threadIdx.x; int lane = t & 63; int xg = t >> 6;
  __shared__ float s_in[5*68];
  __shared__ float s_w[64*25];
  __shared__ float s_out[64*65];
  for (int i = t; i < 1600; i += 256) s_w[i] = w[i];
  for (int i = t; i < 340; i += 256){
    int r = i / 68, cx = i % 68;
    int yy = y + r - 2, gx = cx - 2;
    float v = 0.f;
    if (yy >= 0 && yy < 64 && gx >= 0 && gx < 64) v = in[(b*64 + yy)*64 + gx];
    s_in[r*68 + cx] = v;
  }
  __syncthreads();
  int o = lane;
  float bvv = bias[o];
  float acc[16];
  #pragma unroll
  for (int k = 0; k < 16; k++) acc[k] = bvv;
  #pragma unroll
  for (int ky = 0; ky < 5; ky++){
    float rv[20];
    const float4* p = reinterpret_cast<const float4*>(&s_in[ky*68 + xg*16]);
    #pragma unroll
    for (int q = 0; q < 5; q++){ float4 f = p[q]; rv[q*4]=f.x; rv[q*4+1]=f.y; rv[q*4+2]=f.z; rv[q*4+3]=f.w; }
    #pragma unroll
    for (int kx = 0; kx < 5; kx++){
      float wv = s_w[o*25 + ky*5 + kx];
      #pragma unroll
      for (int k = 0; k < 16; k++) acc[k] = fmaf(rv[k+kx], wv, acc[k]);
    }
  }
  #pragma unroll
  for (int k = 0; k < 16; k++) s_out[o*65 + xg*16 + k] = fmaxf(acc[k], 0.f);
  __syncthreads();
  for (int i = t; i < 4096; i += 256){
    int px = i >> 6, ch = i & 63;
    out[((size_t)(b*64 + y)*64 + px)*64 + ch] = bf16bits(s_out[ch*65 + px]);
  }
}

// ---------------- pack conv weights [O][C][5][5] -> per-tap B-frag bf16 ----
__global__ void k_packconv(const float* __restrict__ w, unsigned short* __restrict__ out){
  int idx = blockIdx.x*256 + threadIdx.x;   // 102400
  if (idx >= 102400) return;
  int j = idx & 7;
  int l = (idx >> 3) & 63;
  int frag = idx >> 9;
  int nt = frag & 3;
  int ks = (frag >> 2) % 10;
  int dy = frag / 40;
  int q = l >> 4, cr = l & 15;
  int k = ks*32 + q*8 + j;
  int kx = k >> 6, ch = k & 63;
  int n = nt*16 + cr;
  out[idx] = bf16bits(w[((n*64 + ch)*5 + dy)*5 + kx]);
}

// ---------------- conv1/conv2 bf16 MFMA implicit GEMM (512 blocks) ---------
// block = (b, yg 0..15, xh 0..1): 4 y-rows x 32 px out.
// wave = (yr = wv>>1: row pair, ph = wv&1: px half) -> 2 rows x 16 px.
// mode 0: relu -> bf16 NHWC. mode 1: relu -> LN(dataN) -> bf16 enc.
__global__ __launch_bounds__(256) void k_convm(const unsigned short* __restrict__ in_bf,
                        const unsigned short* __restrict__ wpack,
                        const float* __restrict__ bias,
                        const float* __restrict__ lng, const float* __restrict__ lnb,
                        unsigned short* __restrict__ out_bf, int mode){
  int bi = blockIdx.x;                  // 512 = 16 b * 16 yg * 2 xh
  int b = bi >> 5; int yg = (bi >> 1) & 15; int xh = bi & 1;
  int t = threadIdx.x; int wv = t >> 6; int l = t & 63;
  int q = l >> 4, cr = l & 15;
  int yr = wv >> 1, ph = wv & 1;
  int p0 = ph*16;                       // px base within the 32-px tile

  __shared__ char lds[8*36*144];        // 8 rows x 36 px x (128B ch + 16B pad)

  for (int ri = 0; ri < 8; ri++){
    int yy = yg*4 + ri - 2;
    bool rok = (yy >= 0 && yy < 64);
    const uint4* src = reinterpret_cast<const uint4*>(in_bf + (size_t)(b*64 + yy)*64*64);
    for (int i = t; i < 288; i += 256){   // 36 px * 8 16B-chunks
      int px = i >> 3, c8 = i & 7;
      uint4 v = {0u,0u,0u,0u};
      int gx = xh*32 + px - 2;
      if (rok && gx >= 0 && gx < 64) v = src[gx*8 + c8];
      *reinterpret_cast<uint4*>(&lds[ri*5184 + px*144 + c8*16]) = v;
    }
  }
  __syncthreads();

  f32x4 acc[2][4];                      // [row r][nt]
  #pragma unroll
  for (int r = 0; r < 2; r++)
    #pragma unroll
    for (int nt = 0; nt < 4; nt++) acc[r][nt] = (f32x4){0.f,0.f,0.f,0.f};

  const bf16x8* wp = reinterpret_cast<const bf16x8*>(wpack);
  for (int dy = 0; dy < 5; dy++){
    for (int ks = 0; ks < 10; ks++){
      bf16x8 Bf[4];
      int fbase = (dy*10 + ks)*4;
      #pragma unroll
      for (int nt = 0; nt < 4; nt++) Bf[nt] = wp[(fbase + nt)*64 + l];
      int aoff = (p0 + cr + (ks >> 1))*144 + (ks & 1)*64 + q*16;
      #pragma unroll
      for (int r = 0; r < 2; r++){
        int ri = yr*2 + r + dy;
        bf16x8 a = *reinterpret_cast<const bf16x8*>(&lds[ri*5184 + aoff]);
        #pragma unroll
        for (int nt = 0; nt < 4; nt++)
          acc[r][nt] = __builtin_amdgcn_mfma_f32_16x16x32_bf16(a, Bf[nt], acc[r][nt], 0, 0, 0);
      }
    }
  }

  float bvv[4];
  #pragma unroll
  for (int nt = 0; nt < 4; nt++) bvv[nt] = bias[nt*16 + cr];

  if (mode == 0){
    #pragma unroll
    for (int r = 0; r < 2; r++){
      int y = yg*4 + yr*2 + r;
      #pragma unroll
      for (int reg = 0; reg < 4; reg++){
        int p = xh*32 + p0 + q*4 + reg;
        size_t base = ((size_t)(b*64 + y)*64 + p)*64;
        #pragma unroll
        for (int nt = 0; nt < 4; nt++)
          out_bf[base + nt*16 + cr] = bf16bits(fmaxf(acc[r][nt][reg] + bvv[nt], 0.f));
      }
    }
  } else {
    float gv[4], bb[4];
    #pragma unroll
    for (int nt = 0; nt < 4; nt++){ gv[nt] = lng[nt*16 + cr]; bb[nt] = lnb[nt*16 + cr]; }
    #pragma unroll
    for (int r = 0; r < 2; r++){
      int y = yg*4 + yr*2 + r;
      #pragma unroll
      for (int reg = 0; reg < 4; reg++){
        int p = xh*32 + p0 + q*4 + reg;
        float v[4]; float s1 = 0.f, s2 = 0.f;
        #pragma unroll
        for (int nt = 0; nt < 4; nt++){
          v[nt] = fmaxf(acc[r][nt][reg] + bvv[nt], 0.f);
          s1 += v[nt]; s2 += v[nt]*v[nt];
        }
        #pragma unroll
        for (int m = 1; m < 16; m <<= 1){ s1 += __shfl_xor(s1, m, 64); s2 += __shfl_xor(s2, m, 64); }
        float mean = s1 * (1.f/64.f);
        float var  = s2 * (1.f/64.f) - mean*mean;
        float rstd = 1.0f/sqrtf(var + 1e-5f);
        size_t base = ((size_t)b*4096 + y*64 + p)*64;
        #pragma unroll
        for (int nt = 0; nt < 4; nt++)
          out_bf[base + nt*16 + cr] = bf16bits((v[nt] - mean)*rstd*gv[nt] + bb[nt]);
      }
    }
  }
}

// ---------------- pack 64x64 f32 [k][n] into B-fragment-ordered bf16 -------
__global__ void k_packw1(const float* __restrict__ w1, unsigned short* __restrict__ out){
  int idx = blockIdx.x*256 + threadIdx.x;   // 4096
  int jj = idx & 7;
  int lane = (idx >> 3) & 63;
  int frag = idx >> 9;
  int ks = frag >> 2, nt = frag & 3;
  int q = lane >> 4, cr = lane & 15;
  int k = ks*32 + q*8 + jj;
  int n = nt*16 + cr;
  out[idx] = bf16bits(w1[k*64 + n]);
}

// ---------------- K/V projection: enc(bf16) @ toK_w, toV_w -> bf16 ---------
__global__ __launch_bounds__(256) void k_projm(const unsigned short* __restrict__ enc,
                       const unsigned short* __restrict__ kpack, const float* __restrict__ bk,
                       const unsigned short* __restrict__ vpack, const float* __restrict__ bvp,
                       unsigned short* __restrict__ K, unsigned short* __restrict__ V){
  int bi = blockIdx.x; int b = bi >> 6; int tile = bi & 63;  // 1024 blocks
  int t = threadIdx.x; int wv = t >> 6; int l = t & 63;
  int q = l >> 4, cr = l & 15;
  int d0 = tile*64 + wv*16;

  const bf16x8* kp = reinterpret_cast<const bf16x8*>(kpack);
  const bf16x8* vp = reinterpret_cast<const bf16x8*>(vpack);
  bf16x8 KB[8], VB[8];
  #pragma unroll
  for (int f = 0; f < 8; f++){ KB[f] = kp[f*64 + l]; VB[f] = vp[f*64 + l]; }

  const unsigned short* er = enc + (size_t)(b*4096 + d0 + cr)*64;
  bf16x8 a0 = *reinterpret_cast<const bf16x8*>(er + q*8);
  bf16x8 a1 = *reinterpret_cast<const bf16x8*>(er + 32 + q*8);

  f32x4 zero = {0.f,0.f,0.f,0.f};
  f32x4 aK[4], aV[4];
  #pragma unroll
  for (int nt = 0; nt < 4; nt++){
    aK[nt] = __builtin_amdgcn_mfma_f32_16x16x32_bf16(a0, KB[nt],     zero,   0, 0, 0);
    aK[nt] = __builtin_amdgcn_mfma_f32_16x16x32_bf16(a1, KB[4 + nt], aK[nt], 0, 0, 0);
    aV[nt] = __builtin_amdgcn_mfma_f32_16x16x32_bf16(a0, VB[nt],     zero,   0, 0, 0);
    aV[nt] = __builtin_amdgcn_mfma_f32_16x16x32_bf16(a1, VB[4 + nt], aV[nt], 0, 0, 0);
  }
  #pragma unroll
  for (int nt = 0; nt < 4; nt++){
    float bkv = bk[nt*16 + cr], bvv = bvp[nt*16 + cr];
    #pragma unroll
    for (int reg = 0; reg < 4; reg++){
      size_t base = ((size_t)b*4096 + d0 + q*4 + reg)*64 + nt*16 + cr;
      K[base] = bf16bits(aK[nt][reg] + bkv);
      V[base] = bf16bits(aV[nt][reg] + bvv);
    }
  }
}

// ---------------- attention K-pass: slot-PAIRED GEMM1 + softmax + frames ---
__global__ __launch_bounds__(256) void k_attnK(const unsigned short* __restrict__ encX,
     const unsigned short* __restrict__ w1pack, const float* __restrict__ mlp1b,
     const float* __restrict__ absc, const float* __restrict__ qg_,
     const float* __restrict__ qb_, const float* __restrict__ w2qc,
     float* __restrict__ att, float* __restrict__ accF){
  int bi = blockIdx.x;                 // 1024 = 16 b * 64 tiles
  int b = bi >> 6, tile = bi & 63;
  int t = threadIdx.x; int wv = t >> 6; int l = t & 63;
  int q = l >> 4, cr = l & 15;
  int m0 = tile*64 + wv*16;
  int drow = m0 + cr;

  __shared__ float s_log[7*64];
  __shared__ float s_absc[7*192];
  __shared__ float s_wq[7*68];
  __shared__ unsigned short s_w1[4096];
  for (int i = t; i < 1344; i += 256) s_absc[i] = absc[b*7*192 + i];
  for (int i = t; i < 476;  i += 256) s_wq[i]   = w2qc[b*7*68 + i];
  {
    const uint4* g = reinterpret_cast<const uint4*>(w1pack);
    uint4* d = reinterpret_cast<uint4*>(s_w1);
    for (int i = t; i < 512; i += 256) d[i] = g[i];
  }

  const unsigned short* er = encX + (size_t)(b*4096 + drow)*64;
  float gx = -0.5f + (float)(drow & 63) * (1.f/63.f);
  float gy = -0.5f + (float)((drow >> 6) & 63) * (1.f/63.f);
  float xb[16], gq[16], bq[16];
  {
    bf16x8 ea = *reinterpret_cast<const bf16x8*>(er + q*8);
    bf16x8 eb = *reinterpret_cast<const bf16x8*>(er + 32 + q*8);
    #pragma unroll
    for (int i = 0; i < 8; i++){ xb[i] = (float)ea[i]; xb[8+i] = (float)eb[i]; }
  }
  #pragma unroll
  for (int h = 0; h < 2; h++){
    int fb = h ? (32 + q*8) : (q*8);
    const float4* g4 = reinterpret_cast<const float4*>(qg_ + fb);
    const float4* b4 = reinterpret_cast<const float4*>(qb_ + fb);
    #pragma unroll
    for (int p = 0; p < 2; p++){
      float4 gg = g4[p], bb = b4[p];
      int o = h*8 + p*4;
      gq[o+0]=gg.x; gq[o+1]=gg.y; gq[o+2]=gg.z; gq[o+3]=gg.w;
      bq[o+0]=bb.x; bq[o+1]=bb.y; bq[o+2]=bb.z; bq[o+3]=bb.w;
    }
  }
  float b1v[4];
  #pragma unroll
  for (int nt = 0; nt < 4; nt++) b1v[nt] = mlp1b[nt*16 + cr];
  __syncthreads();

  const bf16x8* wl = reinterpret_cast<const bf16x8*>(s_w1);
  f32x4 zero = {0.f, 0.f, 0.f, 0.f};

  for (int sp = 0; sp < 4; sp++){
    int s0 = sp*2;
    int np = (sp == 3) ? 1 : 2;          // wave-uniform
    int sB = (np == 2) ? s0 + 1 : s0;
    float x0[16], x1[16];
    float s1a = 0.f, s2a = 0.f, s1b = 0.f, s2b = 0.f;
    {
      const float* Ac = s_absc + s0*192;
      #pragma unroll
      for (int h = 0; h < 2; h++){
        int fb = h ? (32 + q*8) : (q*8);
        const float4* A4 = reinterpret_cast<const float4*>(Ac + fb);
        const float4* B4 = reinterpret_cast<const float4*>(Ac + 64 + fb);
        const float4* C4 = reinterpret_cast<const float4*>(Ac + 128 + fb);
        #pragma unroll
        for (int p = 0; p < 2; p++){
          float4 Av = A4[p], Bv = B4[p], Cv = C4[p];
          int o = h*8 + p*4;
          x0[o+0] = xb[o+0] + gx*Av.x + gy*Bv.x + Cv.x;
          x0[o+1] = xb[o+1] + gx*Av.y + gy*Bv.y + Cv.y;
          x0[o+2] = xb[o+2] + gx*Av.z + gy*Bv.z + Cv.z;
          x0[o+3] = xb[o+3] + gx*Av.w + gy*Bv.w + Cv.w;
        }
      }
      #pragma unroll
      for (int k = 0; k < 16; k++){ s1a += x0[k]; s2a = fmaf(x0[k], x0[k], s2a); }
    }
    {
      const float* Ac = s_absc + sB*192;
      #pragma unroll
      for (int h = 0; h < 2; h++){
        int fb = h ? (32 + q*8) : (q*8);
        const float4* A4 = reinterpret_cast<const float4*>(Ac + fb);
        const float4* B4 = reinterpret_cast<const float4*>(Ac + 64 + fb);
        const float4* C4 = reinterpret_cast<const float4*>(Ac + 128 + fb);
        #pragma unroll
        for (int p = 0; p < 2; p++){
          float4 Av = A4[p], Bv = B4[p], Cv = C4[p];
          int o = h*8 + p*4;
          x1[o+0] = xb[o+0] + gx*Av.x + gy*Bv.x + Cv.x;
          x1[o+1] = xb[o+1] + gx*Av.y + gy*Bv.y + Cv.y;
          x1[o+2] = xb[o+2] + gx*Av.z + gy*Bv.z + Cv.z;
          x1[o+3] = xb[o+3] + gx*Av.w + gy*Bv.w + Cv.w;
        }
      }
      #pragma unroll
      for (int k = 0; k < 16; k++){ s1b += x1[k]; s2b = fmaf(x1[k], x1[k], s2b); }
    }
    s1a += __shfl_xor(s1a, 16, 64); s2a += __shfl_xor(s2a, 16, 64);
    s1b += __shfl_xor(s1b, 16, 64); s2b += __shfl_xor(s2b, 16, 64);
    s1a += __shfl_xor(s1a, 32, 64); s2a += __shfl_xor(s2a, 32, 64);
    s1b += __shfl_xor(s1b, 32, 64); s2b += __shfl_xor(s2b, 32, 64);
    float mA = s1a*(1.f/64.f);
    float rA = 1.0f/sqrtf(s2a*(1.f/64.f) - mA*mA + 1e-5f);
    float mB = s1b*(1.f/64.f);
    float rB = 1.0f/sqrtf(s2b*(1.f/64.f) - mB*mB + 1e-5f);

    bf16x8 a00, a01, a10, a11;
    #pragma unroll
    for (int k = 0; k < 8; k++){
      a00[k] = (__bf16)((x0[k]    - mA)*rA*gq[k]   + bq[k]);
      a01[k] = (__bf16)((x0[8+k]  - mA)*rA*gq[8+k] + bq[8+k]);
      a10[k] = (__bf16)((x1[k]    - mB)*rB*gq[k]   + bq[k]);
      a11[k] = (__bf16)((x1[8+k]  - mB)*rB*gq[8+k] + bq[8+k]);
    }

    f32x4 acc0[4], acc1[4];
    #pragma unroll
    for (int nt = 0; nt < 4; nt++){
      bf16x8 w0 = wl[nt*64 + l];
      bf16x8 w1f = wl[(4 + nt)*64 + l];
      acc0[nt] = __builtin_amdgcn_mfma_f32_16x16x32_bf16(a00, w0,  zero,     0, 0, 0);
      acc0[nt] = __builtin_amdgcn_mfma_f32_16x16x32_bf16(a01, w1f, acc0[nt], 0, 0, 0);
      acc1[nt] = __builtin_amdgcn_mfma_f32_16x16x32_bf16(a10, w0,  zero,     0, 0, 0);
      acc1[nt] = __builtin_amdgcn_mfma_f32_16x16x32_bf16(a11, w1f, acc1[nt], 0, 0, 0);
    }

    float p0[4] = {0.f,0.f,0.f,0.f}, p1[4] = {0.f,0.f,0.f,0.f};
    #pragma unroll
    for (int nt = 0; nt < 4; nt++){
      float wq0 = s_wq[s0*68 + nt*16 + cr];
      float wq1 = s_wq[sB*68 + nt*16 + cr];
      #pragma unroll
      for (int reg = 0; reg < 4; reg++){
        p0[reg] = fmaf(fmaxf(acc0[nt][reg] + b1v[nt], 0.f), wq0, p0[reg]);
        p1[reg] = fmaf(fmaxf(acc1[nt][reg] + b1v[nt], 0.f), wq1, p1[reg]);
      }
    }
    #pragma unroll
    for (int off = 1; off < 16; off <<= 1){
      #pragma unroll
      for (int reg = 0; reg < 4; reg++){
        p0[reg] += __shfl_xor(p0[reg], off, 64);
        p1[reg] += __shfl_xor(p1[reg], off, 64);
      }
    }
    if (cr == 0){
      float c20 = s_wq[s0*68 + 64];
      float c21 = s_wq[sB*68 + 64];
      #pragma unroll
      for (int reg = 0; reg < 4; reg++){
        s_log[s0*64 + wv*16 + q*4 + reg] = (p0[reg] + c20) * 0.125f;
        if (np == 2) s_log[sB*64 + wv*16 + q*4 + reg] = (p1[reg] + c21) * 0.125f;
      }
    }
  }
  __syncthreads();

  // softmax over slots (per d column), store att to LDS + global
  if (t < 64){
    float lv[7];
    #pragma unroll
    for (int s = 0; s < 7; s++) lv[s] = s_log[s*64 + t];
    float mx = lv[0];
    #pragma unroll
    for (int s = 1; s < 7; s++) mx = fmaxf(mx, lv[s]);
    float sm = 0.f;
    #pragma unroll
    for (int s = 0; s < 7; s++){ lv[s] = expf(lv[s] - mx); sm += lv[s]; }
    float inv = 1.0f / sm;
    #pragma unroll
    for (int s = 0; s < 7; s++){
      float a = lv[s] * inv;
      s_log[s*64 + t] = a;
      att[(size_t)(b*7+s)*4096 + tile*64 + t] = a;
    }
  }
  __syncthreads();

  // frames partials: thread (s, r) covers columns r and r+32
  if (t < 224){
    int s = t >> 5, r = t & 31;
    float a1 = s_log[s*64 + r];
    float a2 = s_log[s*64 + r + 32];
    float gx1 = -0.5f + (float)r * (1.f/63.f);
    float gx2 = -0.5f + (float)(r + 32) * (1.f/63.f);
    float gyc = -0.5f + (float)tile * (1.f/63.f);
    float gy2c = gyc*gyc;
    float w0 = a1 + a2;
    float w1 = a1*gx1 + a2*gx2;
    float w2 = w0*gyc;
    float w3 = a1*(gx1*gx1 + gy2c) + a2*(gx2*gx2 + gy2c);
    #pragma unroll
    for (int m = 1; m < 32; m <<= 1){
      w0 += __shfl_xor(w0, m, 64);
      w1 += __shfl_xor(w1, m, 64);
      w2 += __shfl_xor(w2, m, 64);
      w3 += __shfl_xor(w3, m, 64);
    }
    if (r == 0){
      atomicAdd(&accF[(b*7+s)*4 + 0], w0);
      atomicAdd(&accF[(b*7+s)*4 + 1], w1);
      atomicAdd(&accF[(b*7+s)*4 + 2], w2);
      atomicAdd(&accF[(b*7+s)*4 + 3], w3);
    }
  }
}

// ---------------- attention V-pass: slot-PAIRED GEMM1 + weighted reduce ----
__global__ __launch_bounds__(256) void k_attnV(const unsigned short* __restrict__ encX,
     const unsigned short* __restrict__ w1pack, const float* __restrict__ mlp1b,
     const float* __restrict__ absc, const float* __restrict__ qg_,
     const float* __restrict__ qb_, const float* __restrict__ att,
     const float* __restrict__ accF, float* __restrict__ upd){
  int bi = blockIdx.x;                 // 1024
  int b = bi >> 6, tile = bi & 63;
  int t = threadIdx.x; int wv = t >> 6; int l = t & 63;
  int q = l >> 4, cr = l & 15;
  int m0 = tile*64 + wv*16;
  int drow = m0 + cr;

  __shared__ float s_absc[7*192];
  __shared__ float s_att[7*64];
  __shared__ float s_upd[7*64];
  __shared__ float s_inv[7];
  __shared__ unsigned short s_w1[4096];
  for (int i = t; i < 1344; i += 256) s_absc[i] = absc[b*7*192 + i];
  for (int i = t; i < 448;  i += 256){
    s_att[i] = att[(size_t)(b*7 + (i >> 6))*4096 + tile*64 + (i & 63)];
    s_upd[i] = 0.f;
  }
  if (t < 7) s_inv[t] = 1.0f / accF[(b*7 + t)*4];
  {
    const uint4* g = reinterpret_cast<const uint4*>(w1pack);
    uint4* d = reinterpret_cast<uint4*>(s_w1);
    for (int i = t; i < 512; i += 256) d[i] = g[i];
  }

  const unsigned short* er = encX + (size_t)(b*4096 + drow)*64;
  float gx = -0.5f + (float)(drow & 63) * (1.f/63.f);
  float gy = -0.5f + (float)((drow >> 6) & 63) * (1.f/63.f);
  float xb[16], gq[16], bq[16];
  {
    bf16x8 ea = *reinterpret_cast<const bf16x8*>(er + q*8);
    bf16x8 eb = *reinterpret_cast<const bf16x8*>(er + 32 + q*8);
    #pragma unroll
    for (int i = 0; i < 8; i++){ xb[i] = (float)ea[i]; xb[8+i] = (float)eb[i]; }
  }
  #pragma unroll
  for (int h = 0; h < 2; h++){
    int fb = h ? (32 + q*8) : (q*8);
    const float4* g4 = reinterpret_cast<const float4*>(qg_ + fb);
    const float4* b4 = reinterpret_cast<const float4*>(qb_ + fb);
    #pragma unroll
    for (int p = 0; p < 2; p++){
      float4 gg = g4[p], bb = b4[p];
      int o = h*8 + p*4;
      gq[o+0]=gg.x; gq[o+1]=gg.y; gq[o+2]=gg.z; gq[o+3]=gg.w;
      bq[o+0]=bb.x; bq[o+1]=bb.y; bq[o+2]=bb.z; bq[o+3]=bb.w;
    }
  }
  float b1v[4];
  #pragma unroll
  for (int nt = 0; nt < 4; nt++) b1v[nt] = mlp1b[nt*16 + cr];
  __syncthreads();

  const bf16x8* wl = reinterpret_cast<const bf16x8*>(s_w1);
  f32x4 zero = {0.f, 0.f, 0.f, 0.f};

  for (int sp = 0; sp < 4; sp++){
    int s0 = sp*2;
    int np = (sp == 3) ? 1 : 2;
    int sB = (np == 2) ? s0 + 1 : s0;
    float x0[16], x1[16];
    float s1a = 0.f, s2a = 0.f, s1b = 0.f, s2b = 0.f;
    {
      const float* Ac = s_absc + s0*192;
      #pragma unroll
      for (int h = 0; h < 2; h++){
        int fb = h ? (32 + q*8) : (q*8);
        const float4* A4 = reinterpret_cast<const float4*>(Ac + fb);
        const float4* B4 = reinterpret_cast<const float4*>(Ac + 64 + fb);
        const float4* C4 = reinterpret_cast<const float4*>(Ac + 128 + fb);
        #pragma unroll
        for (int p = 0; p < 2; p++){
          float4 Av = A4[p], Bv = B4[p], Cv = C4[p];
          int o = h*8 + p*4;
          x0[o+0] = xb[o+0] + gx*Av.x + gy*Bv.x + Cv.x;
          x0[o+1] = xb[o+1] + gx*Av.y + gy*Bv.y + Cv.y;
          x0[o+2] = xb[o+2] + gx*Av.z + gy*Bv.z + Cv.z;
          x0[o+3] = xb[o+3] + gx*Av.w + gy*Bv.w + Cv.w;
        }
      }
      #pragma unroll
      for (int k = 0; k < 16; k++){ s1a += x0[k]; s2a = fmaf(x0[k], x0[k], s2a); }
    }
    {
      const float* Ac = s_absc + sB*192;
      #pragma unroll
      for (int h = 0; h < 2; h++){
        int fb = h ? (32 + q*8) : (q*8);
        const float4* A4 = reinterpret_cast<const float4*>(Ac + fb);
        const float4* B4 = reinterpret_cast<const float4*>(Ac + 64 + fb);
        const float4* C4 = reinterpret_cast<const float4*>(Ac + 128 + fb);
        #pragma unroll
        for (int p = 0; p < 2; p++){
          float4 Av = A4[p], Bv = B4[p], Cv = C4[p];
          int o = h*8 + p*4;
          x1[o+0] = xb[o+0] + gx*Av.x + gy*Bv.x + Cv.x;
          x1[o+1] = xb[o+1] + gx*Av.y + gy*Bv.y + Cv.y;
          x1[o+2] = xb[o+2] + gx*Av.z + gy*Bv.z + Cv.z;
          x1[o+3] = xb[o+3] + gx*Av.w + gy*Bv.w + Cv.w;
        }
      }
      #pragma unroll
      for (int k = 0; k < 16; k++){ s1b += x1[k]; s2b = fmaf(x1[k], x1[k], s2b); }
    }
    s1a += __shfl_xor(s1a, 16, 64); s2a += __shfl_xor(s2a, 16, 64);
    s1b += __shfl_xor(s1b, 16, 64); s2b += __shfl_xor(s2b, 16, 64);
    s1a += __shfl_xor(s1a, 32, 64); s2a += __shfl_xor(s2a, 32, 64);
    s1b += __shfl_xor(s1b, 32, 64); s2b += __shfl_xor(s2b, 32, 64);
    float mA = s1a*(1.f/64.f);
    float rA = 1.0f/sqrtf(s2a*(1.f/64.f) - mA*mA + 1e-5f);
    float mB = s1b*(1.f/64.f);
    float rB = 1.0f/sqrtf(s2b*(1.f/64.f) - mB*mB + 1e-5f);

    bf16x8 a00, a01, a10, a11;
    #pragma unroll
    for (int k = 0; k < 8; k++){
      a00[k] = (__bf16)((x0[k]    - mA)*rA*gq[k]   + bq[k]);
      a01[k] = (__bf16)((x0[8+k]  - mA)*rA*gq[8+k] + bq[8+k]);
      a10[k] = (__bf16)((x1[k]    - mB)*rB*gq[k]   + bq[k]);
      a11[k] = (__bf16)((x1[8+k]  - mB)*rB*gq[8+k] + bq[8+k]);
    }

    f32x4 acc0[4], acc1[4];
    #pragma unroll
    for (int nt = 0; nt < 4; nt++){
      bf16x8 w0 = wl[nt*64 + l];
      bf16x8 w1f = wl[(4 + nt)*64 + l];
      acc0[nt] = __builtin_amdgcn_mfma_f32_16x16x32_bf16(a00, w0,  zero,     0, 0, 0);
      acc0[nt] = __builtin_amdgcn_mfma_f32_16x16x32_bf16(a01, w1f, acc0[nt], 0, 0, 0);
      acc1[nt] = __builtin_amdgcn_mfma_f32_16x16x32_bf16(a10, w0,  zero,     0, 0, 0);
      acc1[nt] = __builtin_amdgcn_mfma_f32_16x16x32_bf16(a11, w1f, acc1[nt], 0, 0, 0);
    }

    float rsa0 = s_inv[s0], rsa1 = s_inv[sB];
    float wr0[4], wr1[4];
    #pragma unroll
    for (int reg = 0; reg < 4; reg++){
      wr0[reg] = fmaf(s_att[s0*64 + wv*16 + q*4 + reg], rsa0, 1e-8f);
      wr1[reg] = fmaf(s_att[sB*64 + wv*16 + q*4 + reg], rsa1, 1e-8f);
    }
    float pc0[4], pc1[4];
    #pragma unroll
    for (int nt = 0; nt < 4; nt++){
      pc0[nt] = 0.f; pc1[nt] = 0.f;
      #pragma unroll
      for (int reg = 0; reg < 4; reg++){
        pc0[nt] = fmaf(wr0[reg], fmaxf(acc0[nt][reg] + b1v[nt], 0.f), pc0[nt]);
        pc1[nt] = fmaf(wr1[reg], fmaxf(acc1[nt][reg] + b1v[nt], 0.f), pc1[nt]);
      }
    }
    #pragma unroll
    for (int nt = 0; nt < 4; nt++){
      pc0[nt] += __shfl_xor(pc0[nt], 16, 64);
      pc1[nt] += __shfl_xor(pc1[nt], 16, 64);
      pc0[nt] += __shfl_xor(pc0[nt], 32, 64);
      pc1[nt] += __shfl_xor(pc1[nt], 32, 64);
    }
    if (q == 0){
      #pragma unroll
      for (int nt = 0; nt < 4; nt++){
        atomicAdd(&s_upd[s0*64 + nt*16 + cr], pc0[nt]);
        if (np == 2) atomicAdd(&s_upd[sB*64 + nt*16 + cr], pc1[nt]);
      }
    }
  }
  __syncthreads();
  for (int i = t; i < 448; i += 256)
    atomicAdd(&upd[b*448 + i], s_upd[i]);
}

// ---------------- GRU cell + frames finalize + next-phase prep -------------
__global__ void k_gru(float* __restrict__ upd, float* __restrict__ queries,
                      const float* __restrict__ wih, const float* __restrict__ whh,
                      const float* __restrict__ bih, const float* __restrict__ bhh,
                      const float* __restrict__ mlp2w, const float* __restrict__ mlp2b,
                      float* __restrict__ accF, float* __restrict__ ps,
                      const float* __restrict__ qg_, const float* __restrict__ qb_,
                      const float* __restrict__ dw, const float* __restrict__ db,
                      float* __restrict__ absc, float* __restrict__ w2qc){
  int row = blockIdx.x; int t = threadIdx.x;   // 112 x 192
  __shared__ float us[64], hs[64], xs[64], gis[192], ghs[192];
  __shared__ float s_ps3[3];
  if (t < 64){ us[t] = upd[row*64 + t]; hs[t] = queries[row*64 + t]; }
  if (t == 64){
    float sa = accF[row*4+0];
    float ax = accF[row*4+1], ay = accF[row*4+2], ar2 = accF[row*4+3];
    float isa = 1.0f/sa;
    float Wx = ax*isa, Wy = ay*isa;
    float Wg = ar2*isa + 1e-8f*SR2;
    float s2 = Wg - (Wx*Wx + Wy*Wy)*(2.f - W0CONST);
    s_ps3[0] = Wx; s_ps3[1] = Wy; s_ps3[2] = sqrtf(fmaxf(s2, 0.f));
  }
  __syncthreads();
  if (t < 64){
    float a = W0CONST * mlp2b[t];
    for (int i = 0; i < 64; i++) a = fmaf(us[i], mlp2w[i*64 + t], a);
    xs[t] = a;
  }
  __syncthreads();
  float gi = bih[t], gh = bhh[t];
  for (int e = 0; e < 64; e++){
    gi = fmaf(wih[t*64 + e], xs[e], gi);
    gh = fmaf(whh[t*64 + e], hs[e], gh);
  }
  gis[t] = gi; ghs[t] = gh;
  __syncthreads();
  if (t < 64){
    float r = 1.0f/(1.0f + expf(-(gis[t]      + ghs[t])));
    float z = 1.0f/(1.0f + expf(-(gis[64+t]   + ghs[64+t])));
    float n = tanhf(gis[128+t] + r*ghs[128+t]);
    float newq = (1.0f - z)*n + z*hs[t];
    queries[row*64 + t] = newq;
    upd[row*64 + t] = 0.f;
    if (t < 4) accF[row*4 + t] = 0.f;
    if (t < 3) ps[row*3 + t] = s_ps3[t];
    pp_core(row, t, newq, s_ps3[0], s_ps3[1], s_ps3[2],
            qg_, qb_, dw, db, mlp2w, mlp2b, absc, w2qc);
  }
}

// ---------------- heads: alpha, slot_feat(+frames), copy queries -----------
__global__ void k_final(const float* __restrict__ queries, const float* __restrict__ accF,
                        const float* __restrict__ a1w, const float* __restrict__ a1b,
                        const float* __restrict__ a2w, const float* __restrict__ a2b,
                        const float* __restrict__ f1w, const float* __restrict__ f1b,
                        const float* __restrict__ f2w, const float* __restrict__ f2b,
                        float* __restrict__ out){
  int bs = blockIdx.x; int e = threadIdx.x;    // 112 x 64
  __shared__ float qs[64], hf[64], ha[32];
  float q = queries[bs*64 + e];
  qs[e] = q;
  out[bs*64 + e] = q;
  __syncthreads();
  float accf = f1b[e];
  for (int i = 0; i < 64; i++) accf = fmaf(qs[i], f1w[i*64 + e], accf);
  hf[e] = fmaxf(accf, 0.f);
  if (e < 32){
    float acca = a1b[e];
    for (int i = 0; i < 64; i++) acca = fmaf(qs[i], a1w[i*32 + e], acca);
    ha[e] = fmaxf(acca, 0.f);
  }
  __syncthreads();
  if (e < 3){
    float sf = f2b[e];
    for (int o = 0; o < 64; o++) sf = fmaf(hf[o], f2w[o*3 + e], sf);
    float sa = accF[bs*4+0], ax = accF[bs*4+1], ay = accF[bs*4+2], ar2 = accF[bs*4+3];
    float isa = 1.0f/sa;
    float Wx = ax*isa, Wy = ay*isa;
    float Wg = ar2*isa + 1e-8f*SR2;
    float s2 = Wg - (Wx*Wx + Wy*Wy)*(2.f - W0CONST);
    float nv = (e == 0) ? Wx : ((e == 1) ? Wy : sqrtf(fmaxf(s2, 0.f)));
    out[465920 + bs*3 + e] = sf + nv;
  }
  if (e == 32){
    float al = a2b[0];
    for (int o = 0; o < 32; o++) al = fmaf(ha[o], a2w[o], al);
    out[466256 + bs] = 1.0f/(1.0f + expf(-al));
  }
}

// ---------------------------------------------------------------------------
extern "C" void kernel_launch(void* const* d_in, const int* in_sizes, int n_in,
                              void* d_out, int out_size, void* d_ws, size_t ws_size,
                              hipStream_t stream){
  const float* data        = (const float*)d_in[0];
  const float* slot_noise  = (const float*)d_in[1];
  const float* pos_rand    = (const float*)d_in[2];
  const float* conv0_w     = (const float*)d_in[3];
  const float* conv0_b     = (const float*)d_in[4];
  const float* conv1_w     = (const float*)d_in[5];
  const float* conv1_b     = (const float*)d_in[6];
  const float* conv2_w     = (const float*)d_in[7];
  const float* conv2_b     = (const float*)d_in[8];
  const float* dataN_g     = (const float*)d_in[9];
  const float* dataN_b     = (const float*)d_in[10];
  const float* queryN_g    = (const float*)d_in[11];
  const float* queryN_b    = (const float*)d_in[12];
  const float* toK_w       = (const float*)d_in[13];
  const float* toK_b       = (const float*)d_in[14];
  const float* toV_w       = (const float*)d_in[15];
  const float* toV_b       = (const float*)d_in[16];
  const float* dense_w     = (const float*)d_in[17];
  const float* dense_b     = (const float*)d_in[18];
  const float* mlp1_w      = (const float*)d_in[19];
  const float* mlp1_b      = (const float*)d_in[20];
  const float* mlp2_w      = (const float*)d_in[21];
  const float* mlp2_b      = (const float*)d_in[22];
  const float* gru_wih     = (const float*)d_in[23];
  const float* gru_whh     = (const float*)d_in[24];
  const float* gru_bih     = (const float*)d_in[25];
  const float* gru_bhh     = (const float*)d_in[26];
  const float* alpha1_w    = (const float*)d_in[27];
  const float* alpha1_b    = (const float*)d_in[28];
  const float* alpha2_w    = (const float*)d_in[29];
  const float* alpha2_b    = (const float*)d_in[30];
  const float* final1_w    = (const float*)d_in[31];
  const float* final1_b    = (const float*)d_in[32];
  const float* final2_w    = (const float*)d_in[33];
  const float* final2_b    = (const float*)d_in[34];
  const float* slots_mu    = (const float*)d_in[35];
  const float* slots_lsig  = (const float*)d_in[36];

  float* ws   = (float*)d_ws;
  float* bufA = ws;                    // c0_bf (bf16) then encK (bf16)
  float* bufB = bufA + 4194304;        // enc bf16
  float* bufC = bufB + 4194304;        // c1_bf (bf16) then encV (bf16)
  float* attw = bufC + 4194304;        // 458,752 (att, iters 0-2)
  float* queries = attw + 458752;      // 7,168
  float* ps   = queries + 7168;        // 512 ([112][3], 336 used)
  float* absc = ps + 512;              // 21,504 (A/B/cc per (b,s))
  float* accF = absc + 21504;          // 512 ([112][4]: sa, ax, ay, ar2)
  float* upd  = accF + 512;            // 7,168
  float* w2qc = upd + 7168;            // 7,616 ([112][68])
  unsigned short* w1pack = (unsigned short*)(w2qc + 7616);   // 4096 bf16
  unsigned short* kpack  = w1pack + 4096;                    // 4096
  unsigned short* vpack  = kpack + 4096;                     // 4096
  unsigned short* wp1    = vpack + 4096;                     // 102,400
  unsigned short* wp2    = wp1 + 102400;                     // 102,400

  unsigned short* c0_bf = (unsigned short*)bufA;   // conv0 out, NHWC bf16
  unsigned short* c1_bf = (unsigned short*)bufC;   // conv1 out, NHWC bf16
  unsigned short* enc   = (unsigned short*)bufB;   // LN(conv2) bf16
  unsigned short* encK  = (unsigned short*)bufA;   // overwrites c0_bf (done)
  unsigned short* encV  = (unsigned short*)bufC;   // overwrites c1_bf (done)

  float* outq   = (float*)d_out;       // queries [7168]
  float* outatt = outq + 7168;         // att [458752]

  k_prep<<<112, 64, 0, stream>>>(slot_noise, pos_rand, slots_mu, slots_lsig,
                                 queryN_g, queryN_b, dense_w, dense_b, mlp2_w, mlp2_b,
                                 queries, ps, absc, w2qc, accF, upd);
  k_packw1<<<16, 256, 0, stream>>>(mlp1_w, w1pack);
  k_packw1<<<16, 256, 0, stream>>>(toK_w, kpack);
  k_packw1<<<16, 256, 0, stream>>>(toV_w, vpack);
  k_packconv<<<400, 256, 0, stream>>>(conv1_w, wp1);
  k_packconv<<<400, 256, 0, stream>>>(conv2_w, wp2);
  k_conv0<<<1024, 256, 0, stream>>>(data, conv0_w, conv0_b, c0_bf);
  k_convm<<<512, 256, 0, stream>>>(c0_bf, wp1, conv1_b, nullptr, nullptr, c1_bf, 0);
  k_convm<<<512, 256, 0, stream>>>(c1_bf, wp2, conv2_b, dataN_g, dataN_b, enc, 1);
  k_projm<<<1024, 256, 0, stream>>>(enc, kpack, toK_b, vpack, toV_b, encK, encV);

  for (int p = 0; p < 4; p++){
    float* attp = (p == 3) ? outatt : attw;
    k_attnK<<<1024, 256, 0, stream>>>(encK, w1pack, mlp1_b, absc, queryN_g, queryN_b,
                                      w2qc, attp, accF);
    if (p < 3){
      k_attnV<<<1024, 256, 0, stream>>>(encV, w1pack, mlp1_b, absc, queryN_g, queryN_b,
                                        attp, accF, upd);
      k_gru<<<112, 192, 0, stream>>>(upd, queries, gru_wih, gru_whh, gru_bih, gru_bhh,
                                     mlp2_w, mlp2_b, accF, ps, queryN_g, queryN_b,
                                     dense_w, dense_b, absc, w2qc);
    }
  }
  k_final<<<112, 64, 0, stream>>>(queries, accF,
                                  alpha1_w, alpha1_b, alpha2_w, alpha2_b,
                                  final1_w, final1_b, final2_w, final2_b, outq);
}